// Round 16
// baseline (454.101 us; speedup 1.0000x reference)
//
#include <hip/hip_runtime.h>

#define HSZ  32
#define TLEN 1024
#define PS   40   // f16 stride per col in a plane (80 B: 16B-aligned b128 reads)

typedef _Float16 half8 __attribute__((ext_vector_type(8)));
typedef float    f32x4 __attribute__((ext_vector_type(4)));

__device__ __forceinline__ float rcp_f(float x){ return __builtin_amdgcn_rcpf(x); }
__device__ __forceinline__ float exp2_f(float x){ return __builtin_amdgcn_exp2f(x); }
#define SCL_S (-1.442695040888963f)   // sigmoid arg prescale: -log2(e)
#define SCL_T ( 2.885390081777927f)   // tanh arg prescale: +2*log2(e)

__device__ __forceinline__ f32x4 mfma16(half8 a, half8 b, f32x4 c){
  return __builtin_amdgcn_mfma_f32_16x16x32_f16(a, b, c, 0, 0, 0);
}
// LDS-only barrier: drain lgkmcnt without draining vmcnt (x prefetch in flight).
__device__ __forceinline__ void lds_barrier(){
  asm volatile("s_waitcnt lgkmcnt(0)\n\ts_barrier" ::: "memory");
}

// gate quad from prescaled args; paired rcps; updates CV in place.
#define ACT4(A0,A1,A2,A3, CV, OV)                              \
  { float Zi_ = exp2_f(A0), Zf_ = exp2_f(A1);                  \
    float Zg_ = exp2_f(A2), Zo_ = exp2_f(A3);                  \
    float di_ = 1.f+Zi_, df_ = 1.f+Zf_;                        \
    float dg_ = 1.f+Zg_, dq_ = 1.f+Zo_;                        \
    float r1_ = rcp_f(di_*df_);                                \
    float IV_ = r1_*df_, FV_ = r1_*di_;                        \
    float r2_ = rcp_f(dg_*dq_);                                \
    float GV_ = fmaf(-2.f, r2_*dq_, 1.f); OV = r2_*dg_;        \
    CV = fmaf(FV_, CV, IV_*GV_); }

// paired tanh(c) for the wave's two states (same layer): one rcp.
#define TANHPAIR(CA, CB, OA, OB, HA, HB)                       \
  { float ZA_ = exp2_f(SCL_T*(CA)), ZB_ = exp2_f(SCL_T*(CB));  \
    float dA_ = 1.f+ZA_, dB_ = 1.f+ZB_;                        \
    float re_ = rcp_f(dA_*dB_);                                \
    float qA_ = re_*dB_*(OA), qB_ = re_*dA_*(OB);              \
    HA = fmaf(-2.f, qA_, OA); HB = fmaf(-2.f, qB_, OB); }

// ANTI-PHASE SKEWED SCHEDULE, 8 waves / 16-batch tile (2 waves/SIMD):
//   waves 0-3 (L0): 2 D-tiles = states 8wl..8wl+7 of layer 0, runs AHEAD.
//   waves 4-7 (L1): 2 D-tiles = states 8wl..8wl+7 of layer 1.
// Each step = 2 barrier intervals with the groups in OPPOSITE phases:
//   I1: L0 acts(t+1)+write h0(t+1)      ||  L1 reads h0(t),h1(t-1) + 8 MFMA
//   I2: L0 reads h0(t+1) + 4 MFMA(t+2)  ||  L1 acts(t)+write h1(t)
// Every SIMD hosts one L0 + one L1 wave -> in each interval one wave drives
// the (quarter-rate) trans pipe while the other's ds_read/MFMA latency hides
// under it. Breaks the lockstep burst/idle alternation of R8-R14.
// Race audit: h0 parity double-buffered (write@(t+1)&1 in I1, L1 reads @t&1
// same interval -> disjoint); h1 single-buffered (read I1 drained at BAR1,
// write I2, re-read after BAR2). Barriers: 2 per step, both wave groups.
// h f16-hi only; weights hi+lo split; permuted A-rows (quad in-lane).
__global__ __launch_bounds__(512, 2) void lstm2_skew(
    const float* __restrict__ x,
    const float* __restrict__ Wih0, const float* __restrict__ Whh0,
    const float* __restrict__ bih0, const float* __restrict__ bhh0,
    const float* __restrict__ Wih1, const float* __restrict__ Whh1,
    const float* __restrict__ bih1, const float* __restrict__ bhh1,
    const float* __restrict__ Wfc,  const float* __restrict__ bfc,
    float* __restrict__ out, int Tn)
{
  __shared__ __align__(16) _Float16 H0[2][16*PS];   // h0, parity double-buffered
  __shared__ __align__(16) _Float16 H1[16*PS];      // h1, single-buffered
  __shared__ float sc[32*17];                       // FC scratch

  const int tid = threadIdx.x;
  const int w   = tid >> 6;
  const int l   = tid & 63;
  const int col = l & 15;        // batch col == A tile-row index
  const int g   = l >> 4;        // k-group == D row-group
  const int b0  = blockIdx.x * 16;
  const bool isL0 = (w < 4);
  const int wl  = isL0 ? w : (w - 4);    // group-local id: states 8wl..8wl+7

  const int rdI = col*PS + 8*g;          // b128 read (16B-aligned)
  const int wrA = col*PS + 8*wl + g;     // state 8wl+g
  const int wrB = wrA + 4;               // state 8wl+4+g
  const float sA = ((col & 3) == 2) ? SCL_T : SCL_S;
  const float scj[4] = {SCL_S, SCL_S, SCL_T, SCL_S};
  const f32x4 zero4 = {0.f, 0.f, 0.f, 0.f};
  const int prowA = 32*(col & 3) + 8*wl + (col >> 2);   // tile A permuted row

  for (int i = tid; i < (2*16 + 16)*PS; i += 512) (&H0[0][0])[i] = (_Float16)0.0f;

  const float* xp = x + (size_t)(b0 + col) * Tn;
  const int Tm1 = Tn - 1;

  // ---- per-role weights (A-side hi/lo, prescaled) and D-side constants ----
  half8 WhA, WlA, WhB, WlB;        // L0: Whh0 tiles A,B | L1: Whh1 tiles A,B
  half8 WIhA, WIlA, WIhB, WIlB;    // L1 only: Wih1 tiles A,B
  float wxA[4], wxB[4], bsA[4], bsB[4];   // L0 only
  f32x4 bias1A, bias1B;                    // L1 only

  if (isL0){
    const float* pA = Whh0 + prowA*HSZ + 8*g;
    const float* pB = pA + 4*HSZ;
    #pragma unroll
    for (int j = 0; j < 8; ++j){
      float vA = pA[j]*sA, vB = pB[j]*sA;
      _Float16 a = (_Float16)vA; WhA[j] = a; WlA[j] = (_Float16)(vA - (float)a);
      _Float16 b = (_Float16)vB; WhB[j] = b; WlB[j] = (_Float16)(vB - (float)b);
    }
    #pragma unroll
    for (int j = 0; j < 4; ++j){
      int rA = 32*j + 8*wl + g, rB = rA + 4;
      wxA[j] = Wih0[rA] * scj[j];
      wxB[j] = Wih0[rB] * scj[j];
      bsA[j] = (bih0[rA] + bhh0[rA]) * scj[j];
      bsB[j] = (bih0[rB] + bhh0[rB]) * scj[j];
    }
  } else {
    const float* hA_ = Whh1 + prowA*HSZ + 8*g;
    const float* hB_ = hA_ + 4*HSZ;
    const float* iA_ = Wih1 + prowA*HSZ + 8*g;
    const float* iB_ = iA_ + 4*HSZ;
    #pragma unroll
    for (int j = 0; j < 8; ++j){
      float v0 = hA_[j]*sA, v1 = hB_[j]*sA, v2 = iA_[j]*sA, v3 = iB_[j]*sA;
      _Float16 a = (_Float16)v0; WhA[j]  = a; WlA[j]  = (_Float16)(v0 - (float)a);
      _Float16 b = (_Float16)v1; WhB[j]  = b; WlB[j]  = (_Float16)(v1 - (float)b);
      _Float16 c = (_Float16)v2; WIhA[j] = c; WIlA[j] = (_Float16)(v2 - (float)c);
      _Float16 d = (_Float16)v3; WIhB[j] = d; WIlB[j] = (_Float16)(v3 - (float)d);
    }
    #pragma unroll
    for (int j = 0; j < 4; ++j){
      int rA = 32*j + 8*wl + g, rB = rA + 4;
      bias1A[j] = (bih1[rA] + bhh1[rA]) * scj[j];
      bias1B[j] = (bih1[rB] + bhh1[rB]) * scj[j];
    }
  }

  float c0A = 0.f, c0B = 0.f;      // L0 cell states
  float c1A = 0.f, c1B = 0.f;      // L1 cell states
  float h1Av = 0.f, h1Bv = 0.f;    // L1 finals

  __syncthreads();   // [A] zero-init visible

  // ---- prologue: L0 scalar step t=0 (h0(-1)=0 -> no MFMA), write h0(0) ----
  if (isL0){
    float x0 = xp[0];
    float oA_, oB_, h0A, h0B;
    ACT4(fmaf(x0,wxA[0],bsA[0]), fmaf(x0,wxA[1],bsA[1]),
         fmaf(x0,wxA[2],bsA[2]), fmaf(x0,wxA[3],bsA[3]), c0A, oA_);
    ACT4(fmaf(x0,wxB[0],bsB[0]), fmaf(x0,wxB[1],bsB[1]),
         fmaf(x0,wxB[2],bsB[2]), fmaf(x0,wxB[3],bsB[3]), c0B, oB_);
    TANHPAIR(c0A, c0B, oA_, oB_, h0A, h0B);
    H0[0][wrA] = (_Float16)h0A;
    H0[0][wrB] = (_Float16)h0B;
  }
  __syncthreads();   // [B] h0(0) visible

  if (isL0){
    // ========== LAYER 0: runs one step ahead ==========
    // prime: MFMA for step 1 (reads h0(0)), so I1 of cycle 0 can do acts(1)
    half8 Bh0 = *(const half8*)&H0[0][rdI];
    f32x4 eA, eB;
    {
      float x1 = xp[1];
      eA[0] = fmaf(x1, wxA[0], bsA[0]); eA[1] = fmaf(x1, wxA[1], bsA[1]);
      eA[2] = fmaf(x1, wxA[2], bsA[2]); eA[3] = fmaf(x1, wxA[3], bsA[3]);
      eB[0] = fmaf(x1, wxB[0], bsB[0]); eB[1] = fmaf(x1, wxB[1], bsB[1]);
      eB[2] = fmaf(x1, wxB[2], bsB[2]); eB[3] = fmaf(x1, wxB[3], bsB[3]);
      eA = mfma16(WhA, Bh0, eA);  eB = mfma16(WhB, Bh0, eB);
      eA = mfma16(WlA, Bh0, eA);  eB = mfma16(WlB, Bh0, eB);
    }
    float xc = xp[2 <= Tm1 ? 2 : Tm1];   // x(t+2), consumed in I2

#define L0BODY(Q, XNI)                                                     \
    {                                                                      \
      float xn = xp[(XNI)];             /* x(t+3), stays in flight */      \
      /* I1: acts for step t+1, write h0(t+1) */                           \
      float oA_, oB_, h0A, h0B;                                            \
      ACT4(eA[0],eA[1],eA[2],eA[3], c0A, oA_);                             \
      ACT4(eB[0],eB[1],eB[2],eB[3], c0B, oB_);                             \
      TANHPAIR(c0A, c0B, oA_, oB_, h0A, h0B);                              \
      H0[(Q)][wrA] = (_Float16)h0A;                                        \
      H0[(Q)][wrB] = (_Float16)h0B;                                        \
      lds_barrier();                     /* BAR1 */                        \
      /* I2: read h0(t+1), MFMA for step t+2 */                            \
      Bh0 = *(const half8*)&H0[(Q)][rdI];                                  \
      eA[0] = fmaf(xc, wxA[0], bsA[0]); eA[1] = fmaf(xc, wxA[1], bsA[1]);  \
      eA[2] = fmaf(xc, wxA[2], bsA[2]); eA[3] = fmaf(xc, wxA[3], bsA[3]);  \
      eB[0] = fmaf(xc, wxB[0], bsB[0]); eB[1] = fmaf(xc, wxB[1], bsB[1]);  \
      eB[2] = fmaf(xc, wxB[2], bsB[2]); eB[3] = fmaf(xc, wxB[3], bsB[3]);  \
      eA = mfma16(WhA, Bh0, eA);  eB = mfma16(WhB, Bh0, eB);               \
      eA = mfma16(WlA, Bh0, eA);  eB = mfma16(WlB, Bh0, eB);               \
      lds_barrier();                     /* BAR2 */                        \
      xc = xn;                                                             \
    }

    for (int T0 = 0; T0 < Tn; T0 += 2){
      L0BODY(1, (T0+3 <= Tm1) ? T0+3 : Tm1);
      L0BODY(0, (T0+4 <= Tm1) ? T0+4 : Tm1);
    }
#undef L0BODY
  } else {
    // ========== LAYER 1: consumes h0(t), h1(t-1) ==========
#define L1BODY(R)                                                          \
    {                                                                      \
      /* I1: read frags, 8 MFMA for step t */                              \
      half8 Bh0 = *(const half8*)&H0[(R)][rdI];                            \
      half8 Bh1 = *(const half8*)&H1[rdI];                                 \
      f32x4 uA = mfma16(WhA, Bh1, bias1A);                                 \
      f32x4 uB = mfma16(WhB, Bh1, bias1B);                                 \
      f32x4 vA = mfma16(WIhA, Bh0, zero4);                                 \
      f32x4 vB = mfma16(WIhB, Bh0, zero4);                                 \
      uA = mfma16(WlA, Bh1, uA);   uB = mfma16(WlB, Bh1, uB);              \
      vA = mfma16(WIlA, Bh0, vA);  vB = mfma16(WIlB, Bh0, vB);             \
      lds_barrier();                     /* BAR1 */                        \
      /* I2: acts for step t, write h1(t) */                               \
      f32x4 aA = uA + vA, aB = uB + vB;                                    \
      float oA_, oB_;                                                      \
      ACT4(aA[0],aA[1],aA[2],aA[3], c1A, oA_);                             \
      ACT4(aB[0],aB[1],aB[2],aB[3], c1B, oB_);                             \
      TANHPAIR(c1A, c1B, oA_, oB_, h1Av, h1Bv);                            \
      H1[wrA] = (_Float16)h1Av;                                            \
      H1[wrB] = (_Float16)h1Bv;                                            \
      lds_barrier();                     /* BAR2 */                        \
    }

    for (int T0 = 0; T0 < Tn; T0 += 2){
      L1BODY(0);
      L1BODY(1);
    }
#undef L1BODY
  }

  // ---- FC head: out[b0+c] = dot(h1_final[:,c], Wfc) + bfc ----
  __syncthreads();   // [C]
  if (!isL0){
    sc[(8*wl + g)*17 + col]     = h1Av;
    sc[(8*wl + 4 + g)*17 + col] = h1Bv;
  }
  __syncthreads();   // [D]
  if (tid < 16){
    float acc = bfc[0];
    #pragma unroll 8
    for (int k = 0; k < HSZ; ++k) acc = fmaf(sc[k*17 + tid], Wfc[k], acc);
    out[b0 + tid] = acc;
  }
}

extern "C" void kernel_launch(void* const* d_in, const int* in_sizes, int n_in,
                              void* d_out, int out_size, void* d_ws, size_t ws_size,
                              hipStream_t stream) {
  const float* x    = (const float*)d_in[0];
  const float* Wih0 = (const float*)d_in[1];
  const float* Whh0 = (const float*)d_in[2];
  const float* bih0 = (const float*)d_in[3];
  const float* bhh0 = (const float*)d_in[4];
  const float* Wih1 = (const float*)d_in[5];
  const float* Whh1 = (const float*)d_in[6];
  const float* bih1 = (const float*)d_in[7];
  const float* bhh1 = (const float*)d_in[8];
  const float* Wfc  = (const float*)d_in[9];
  const float* bfc  = (const float*)d_in[10];
  float* out = (float*)d_out;

  const int Tn = TLEN;
  const int B  = in_sizes[0] / Tn;     // x is (B, T, 1)

  dim3 block(512);
  dim3 grid(B / 16);
  hipLaunchKernelGGL(lstm2_skew, grid, block, 0, stream,
                     x, Wih0, Whh0, bih0, bhh0, Wih1, Whh1, bih1, bhh1,
                     Wfc, bfc, out, Tn);
}